// Round 6
// baseline (89.953 us; speedup 1.0000x reference)
//
#include <hip/hip_runtime.h>
#include <hip/hip_fp16.h>
#include <math.h>

#define BATCH 8
#define NSLOT 256
#define DDIM  256
#define HID   128
#define NREL  8

typedef _Float16 half8 __attribute__((ext_vector_type(8)));
typedef float float4v __attribute__((ext_vector_type(4)));

union U8 {
  uint32_t u[4];
  _Float16 f[8];
  half8 v;
  float4 f4;
};

// ---------------------------------------------------------------------------
// R19: INSTRUMENTATION round. Byte-exact revert to R14 (session best, 79.65us)
// plus ONE duplicated pair_kernel dispatch. pair is idempotent (deterministic,
// writes identical values to identical addresses), so the result is unchanged;
// dur_us - 79.65 ~= pair_exec + ~3.5us dispatch overhead. Four structure bets
// (R15 coop / R16 mega / R17 strips / R18 IT=4) all lost to R14 while the
// fills monopolize the top-5 counter table — this round buys the proj/pair
// split that every further decision needs.
// d_ws layout: P f16[2048][256] at offset 0 (1 MB).
//
// MFMA maps (HW-validated R5-R12): A[m=lane&15][k=(lane>>4)*8+u],
//  B[k=(lane>>4)*8+u][n=lane&15], D[m=(lane>>4)*4+reg][n=lane&15].
// ---------------------------------------------------------------------------

// proj: P[r][c] = dot(slots[r], concatW[:,c]) + (c<128 ? b1[c] : 0)
//   concatW[k][c] = (c<128) ? W1[k][c] : W1[256+k][c-128]
// One wave per 16x16 output tile, 4 c-tiles per 256-thread block.
__global__ __launch_bounds__(256) void proj_kernel(
    const float* __restrict__ slots, const float* __restrict__ W1,
    const float* __restrict__ b1, _Float16* __restrict__ P) {
  const int lane = threadIdx.x & 63;
  const int w    = threadIdx.x >> 6;
  const int lo16 = lane & 15;
  const int kg   = lane >> 4;
  const int row0 = blockIdx.y * 16;
  const int c    = (blockIdx.x * 4 + w) * 16 + lo16;

  // B-frag: bf[ks].f[u] = concatW[ks*32+kg*8+u][c]  (stride-128 dword loads)
  const float* Wcol =
      (c < HID) ? (W1 + c) : (W1 + (size_t)DDIM * HID + (c - HID));
  U8 bf[8];
#pragma unroll
  for (int ks = 0; ks < 8; ++ks) {
    const int kb = ks * 32 + kg * 8;
#pragma unroll
    for (int u = 0; u < 8; ++u)
      bf[ks].f[u] = (_Float16)Wcol[(size_t)(kb + u) * HID];
  }

  float4v acc = {0.0f, 0.0f, 0.0f, 0.0f};
  const float* srow = slots + (size_t)(row0 + lo16) * DDIM;
#pragma unroll
  for (int ks = 0; ks < 8; ++ks) {
    const float4 x0 = *(const float4*)(srow + ks * 32 + kg * 8);
    const float4 x1 = *(const float4*)(srow + ks * 32 + kg * 8 + 4);
    U8 a;
    a.f[0] = (_Float16)x0.x; a.f[1] = (_Float16)x0.y;
    a.f[2] = (_Float16)x0.z; a.f[3] = (_Float16)x0.w;
    a.f[4] = (_Float16)x1.x; a.f[5] = (_Float16)x1.y;
    a.f[6] = (_Float16)x1.z; a.f[7] = (_Float16)x1.w;
    acc = __builtin_amdgcn_mfma_f32_16x16x32_f16(a.v, bf[ks].v, acc, 0, 0, 0);
  }

  const float bias = (c < HID) ? b1[c] : 0.0f;
#pragma unroll
  for (int reg = 0; reg < 4; ++reg)
    P[(size_t)(row0 + kg * 4 + reg) * 256 + c] = (_Float16)(acc[reg] + bias);
}

// pair (R14-validated, session-best config): i-tile 8, 1024 blocks x 256 thr
// (4 waves/SIMD), one tiny Pi LDS stage + one barrier, W2 direct scalar loads.
// out[b,i,j,r] = sigmoid( sum_k relu(P[b,i,k]+P[b,j,128+k]) * W2[k,r] + b2[r] )
__global__ __launch_bounds__(256) void pair_kernel(
    const _Float16* __restrict__ P, const float* __restrict__ W2,
    const float* __restrict__ b2, float* __restrict__ out) {
  __shared__ uint32_t PiL[8 * 68];

  const int tid  = threadIdx.x;
  const int w    = tid >> 6;
  const int lane = tid & 63;
  const int n    = lane & 15;
  const int kg   = lane >> 4;

  const int b  = blockIdx.z;
  const int i0 = blockIdx.y * 8;
  const int j0 = blockIdx.x * 64 + w * 16;
  const _Float16* Pb = P + (size_t)b * NSLOT * 256;

  if (tid < 128) {  // stage Pi: 8 rows x 128 f16
    const int r  = tid >> 4;
    const int ch = tid & 15;
    const float4 t = *(const float4*)(Pb + (size_t)(i0 + r) * 256 + ch * 8);
    *(float4*)&PiL[r * 68 + ch * 4] = t;
  }

  // W2 B-frag direct: w2f[kq].f[u] = (n<8) ? (f16)W2[(kq*32+kg*8+u)*8+n] : 0
  U8 w2f[4];
#pragma unroll
  for (int kq = 0; kq < 4; ++kq) {
    const int kb = kq * 32 + kg * 8;
#pragma unroll
    for (int u = 0; u < 8; ++u) {
      const float v = W2[(kb + u) * NREL + (n & 7)];  // 4KB, L1-resident
      w2f[kq].f[u] = (n < NREL) ? (_Float16)v : (_Float16)0.0f;
    }
  }

  const float b2v = (n < NREL) ? b2[n & 7] : 0.0f;

  U8 pj[4];
#pragma unroll
  for (int kq = 0; kq < 4; ++kq)
    pj[kq].f4 =
        *(const float4*)(Pb + (size_t)(j0 + n) * 256 + HID + kq * 32 + kg * 8);

  __syncthreads();

#pragma unroll
  for (int i = 0; i < 8; ++i) {
    float4v acc = {0.0f, 0.0f, 0.0f, 0.0f};
#pragma unroll
    for (int kq = 0; kq < 4; ++kq) {
      U8 pi;
      pi.f4 = *(const float4*)&PiL[i * 68 + kq * 16 + kg * 4];  // broadcast
      U8 h;
      h.v = __builtin_elementwise_max(pj[kq].v + pi.v, (half8)(_Float16)0.0f);
      acc = __builtin_amdgcn_mfma_f32_16x16x32_f16(h.v, w2f[kq].v, acc, 0, 0, 0);
    }
    if (n < NREL) {
      float* obase =
          out + (((size_t)b * NSLOT + (i0 + i)) * NSLOT + j0) * NREL + n;
#pragma unroll
      for (int reg = 0; reg < 4; ++reg) {
        const int jrow = kg * 4 + reg;
        const float x = acc[reg] + b2v;
        obase[jrow * NREL] = __builtin_amdgcn_rcpf(1.0f + __expf(-x));
      }
    }
  }
}

extern "C" void kernel_launch(void* const* d_in, const int* in_sizes, int n_in,
                              void* d_out, int out_size, void* d_ws,
                              size_t ws_size, hipStream_t stream) {
  const float* slots = (const float*)d_in[0];  // [8,256,256]
  const float* W1    = (const float*)d_in[1];  // [512,128]
  const float* b1    = (const float*)d_in[2];  // [128]
  const float* W2    = (const float*)d_in[3];  // [128,8]
  const float* b2    = (const float*)d_in[4];  // [8]
  float* out  = (float*)d_out;                 // [8,256,256,8]
  _Float16* P = (_Float16*)d_ws;               // 1 MB

  proj_kernel<<<dim3(4, 128), 256, 0, stream>>>(slots, W1, b1, P);
  pair_kernel<<<dim3(NSLOT / 64, NSLOT / 8, BATCH), 256, 0, stream>>>(P, W2,
                                                                      b2, out);
  // R19 instrumentation: duplicated idempotent dispatch. dur_us delta vs the
  // 79.65us R14 baseline ~= pair_exec + dispatch overhead.
  pair_kernel<<<dim3(NSLOT / 64, NSLOT / 8, BATCH), 256, 0, stream>>>(P, W2,
                                                                      b2, out);
}

// Round 7
// 78.079 us; speedup vs baseline: 1.1521x; 1.1521x over previous
//
#include <hip/hip_runtime.h>
#include <hip/hip_fp16.h>
#include <math.h>

#define BATCH 8
#define NSLOT 256
#define DDIM  256
#define HID   128
#define NREL  8

typedef _Float16 half8 __attribute__((ext_vector_type(8)));
typedef float float4v __attribute__((ext_vector_type(4)));

union U8 {
  uint32_t u[4];
  _Float16 f[8];
  half8 v;
  float4 f4;
};

union U4 {
  uint32_t u[2];
  _Float16 f[4];
  uint2 u2;
};

// ---------------------------------------------------------------------------
// R20: single-variable fix of proj's scattered slot loads. R19 instrumentation
// pinned the split: pair+ovh = 10.3us, hence proj ~= 20-26us (~10x its pipe
// model) — proj is the cost center. Invariant across both slow proj variants
// (R0 projA, R14 proj) is the per-lane-row scattered slots read (16 instrs x
// 64 cache lines each). Fix: stage the 16-row slot tile to LDS with fully
// coalesced float4 loads (4/thread), cvt f16 during staging; A-frags become
// single ds_read_b128 (row pad 264 f16 -> 2-way bank aliasing = free, m136).
// Grid, W-frag loads, stores, and the ENTIRE pair kernel are byte-identical
// to R14 (session best 79.65us). d_ws: P f16[2048][256] at 0 (1 MB).
//
// MFMA maps (HW-validated R5-R12): A[m=lane&15][k=(lane>>4)*8+u],
//  B[k=(lane>>4)*8+u][n=lane&15], D[m=(lane>>4)*4+reg][n=lane&15].
// ---------------------------------------------------------------------------

// proj: P[r][c] = dot(slots[r], concatW[:,c]) + (c<128 ? b1[c] : 0)
//   concatW[k][c] = (c<128) ? W1[k][c] : W1[256+k][c-128]
__global__ __launch_bounds__(256) void proj_kernel(
    const float* __restrict__ slots, const float* __restrict__ W1,
    const float* __restrict__ b1, _Float16* __restrict__ P) {
  __shared__ _Float16 SL[16 * 264];  // 16 rows x (256 + 8 pad) f16 = 8.25 KB

  const int tid  = threadIdx.x;
  const int w    = tid >> 6;
  const int lane = tid & 63;
  const int lo16 = lane & 15;
  const int kg   = lane >> 4;
  const int row0 = blockIdx.y * 16;
  const int c    = (blockIdx.x * 4 + w) * 16 + lo16;

  // ---- issue coalesced slot-tile loads first (longest latency) ----
  // 16 rows x 256 f32 = 1024 float4s; 4 per thread; each wave-load = 1 KB
  // contiguous. idx p*256+tid -> row idx>>6, col4 (idx&63)*4.
  float4 sv[4];
  {
    const float* gbase = slots + (size_t)row0 * DDIM;
#pragma unroll
    for (int p = 0; p < 4; ++p) {
      const int idx = p * 256 + tid;
      sv[p] = *(const float4*)(gbase + (idx >> 6) * DDIM + (idx & 63) * 4);
    }
  }

  // ---- W B-frags (R14-identical strided dwords, L2-resident) ----
  const float* Wcol =
      (c < HID) ? (W1 + c) : (W1 + (size_t)DDIM * HID + (c - HID));
  U8 bf[8];
#pragma unroll
  for (int ks = 0; ks < 8; ++ks) {
    const int kb = ks * 32 + kg * 8;
#pragma unroll
    for (int u = 0; u < 8; ++u)
      bf[ks].f[u] = (_Float16)Wcol[(size_t)(kb + u) * HID];
  }

  // ---- cvt + LDS write (b64, dense conflict-free) ----
#pragma unroll
  for (int p = 0; p < 4; ++p) {
    const int idx = p * 256 + tid;
    U4 h;
    h.f[0] = (_Float16)sv[p].x; h.f[1] = (_Float16)sv[p].y;
    h.f[2] = (_Float16)sv[p].z; h.f[3] = (_Float16)sv[p].w;
    *(uint2*)&SL[(idx >> 6) * 264 + (idx & 63) * 4] = h.u2;
  }

  __syncthreads();

  // ---- A-frags from LDS (one ds_read_b128 per ks) + MFMA ----
  float4v acc = {0.0f, 0.0f, 0.0f, 0.0f};
#pragma unroll
  for (int ks = 0; ks < 8; ++ks) {
    U8 a;
    a.f4 = *(const float4*)&SL[lo16 * 264 + ks * 32 + kg * 8];
    acc = __builtin_amdgcn_mfma_f32_16x16x32_f16(a.v, bf[ks].v, acc, 0, 0, 0);
  }

  const float bias = (c < HID) ? b1[c] : 0.0f;
#pragma unroll
  for (int reg = 0; reg < 4; ++reg)
    P[(size_t)(row0 + kg * 4 + reg) * 256 + c] = (_Float16)(acc[reg] + bias);
}

// pair (byte-identical to R14/R19, session-best config): i-tile 8, 1024
// blocks x 256 thr, one tiny Pi LDS stage + one barrier, W2 direct loads.
// out[b,i,j,r] = sigmoid( sum_k relu(P[b,i,k]+P[b,j,128+k]) * W2[k,r] + b2[r] )
__global__ __launch_bounds__(256) void pair_kernel(
    const _Float16* __restrict__ P, const float* __restrict__ W2,
    const float* __restrict__ b2, float* __restrict__ out) {
  __shared__ uint32_t PiL[8 * 68];

  const int tid  = threadIdx.x;
  const int w    = tid >> 6;
  const int lane = tid & 63;
  const int n    = lane & 15;
  const int kg   = lane >> 4;

  const int b  = blockIdx.z;
  const int i0 = blockIdx.y * 8;
  const int j0 = blockIdx.x * 64 + w * 16;
  const _Float16* Pb = P + (size_t)b * NSLOT * 256;

  if (tid < 128) {  // stage Pi: 8 rows x 128 f16
    const int r  = tid >> 4;
    const int ch = tid & 15;
    const float4 t = *(const float4*)(Pb + (size_t)(i0 + r) * 256 + ch * 8);
    *(float4*)&PiL[r * 68 + ch * 4] = t;
  }

  // W2 B-frag direct: w2f[kq].f[u] = (n<8) ? (f16)W2[(kq*32+kg*8+u)*8+n] : 0
  U8 w2f[4];
#pragma unroll
  for (int kq = 0; kq < 4; ++kq) {
    const int kb = kq * 32 + kg * 8;
#pragma unroll
    for (int u = 0; u < 8; ++u) {
      const float v = W2[(kb + u) * NREL + (n & 7)];  // 4KB, L1-resident
      w2f[kq].f[u] = (n < NREL) ? (_Float16)v : (_Float16)0.0f;
    }
  }

  const float b2v = (n < NREL) ? b2[n & 7] : 0.0f;

  U8 pj[4];
#pragma unroll
  for (int kq = 0; kq < 4; ++kq)
    pj[kq].f4 =
        *(const float4*)(Pb + (size_t)(j0 + n) * 256 + HID + kq * 32 + kg * 8);

  __syncthreads();

#pragma unroll
  for (int i = 0; i < 8; ++i) {
    float4v acc = {0.0f, 0.0f, 0.0f, 0.0f};
#pragma unroll
    for (int kq = 0; kq < 4; ++kq) {
      U8 pi;
      pi.f4 = *(const float4*)&PiL[i * 68 + kq * 16 + kg * 4];  // broadcast
      U8 h;
      h.v = __builtin_elementwise_max(pj[kq].v + pi.v, (half8)(_Float16)0.0f);
      acc = __builtin_amdgcn_mfma_f32_16x16x32_f16(h.v, w2f[kq].v, acc, 0, 0, 0);
    }
    if (n < NREL) {
      float* obase =
          out + (((size_t)b * NSLOT + (i0 + i)) * NSLOT + j0) * NREL + n;
#pragma unroll
      for (int reg = 0; reg < 4; ++reg) {
        const int jrow = kg * 4 + reg;
        const float x = acc[reg] + b2v;
        obase[jrow * NREL] = __builtin_amdgcn_rcpf(1.0f + __expf(-x));
      }
    }
  }
}

extern "C" void kernel_launch(void* const* d_in, const int* in_sizes, int n_in,
                              void* d_out, int out_size, void* d_ws,
                              size_t ws_size, hipStream_t stream) {
  const float* slots = (const float*)d_in[0];  // [8,256,256]
  const float* W1    = (const float*)d_in[1];  // [512,128]
  const float* b1    = (const float*)d_in[2];  // [128]
  const float* W2    = (const float*)d_in[3];  // [128,8]
  const float* b2    = (const float*)d_in[4];  // [8]
  float* out  = (float*)d_out;                 // [8,256,256,8]
  _Float16* P = (_Float16*)d_ws;               // 1 MB

  proj_kernel<<<dim3(4, 128), 256, 0, stream>>>(slots, W1, b1, P);
  pair_kernel<<<dim3(NSLOT / 64, NSLOT / 8, BATCH), 256, 0, stream>>>(P, W2,
                                                                      b2, out);
}